// Round 12
// baseline (273.415 us; speedup 1.0000x reference)
//
#include <hip/hip_runtime.h>

// ResNetBlock_MoE: B=64,C=64,H=W=56,E=8,TOPK=2. f32 in / f32 out.
// out = sum_k w_k*relu(bn2(conv2(relu(bn1(conv1(x,e)))))+x), plus dense_w.
//
// R11 post-mortem (WIN 446->270us): A-in-LDS (lgkmcnt) + B-global depth-2
// prefetch (vmcnt) fixed the in-order-queue stall. Now LDS read pipe is top
// consumer: 1 ds_read_b128 per MFMA (8 waves re-read same A). R12: N=32 per
// wave (two B-frags/stream) -> each A ds_read feeds 2 MFMAs; 512-thr blocks
// cover N=256, grid 13x64; xconv GAP sums from LDS f32 copy (kills 51MB
// HBM re-read). Static __device__ scratch (d_ws unusable per R1/R2).

#define BATCH 64
#define CH    64
#define HW_   3136            // 56*56
#define IMG_  (CH*HW_)        // 200704
#define NE    8
#define JOBS  128
#define PWSZ  36864           // per-expert packed weights: 18*64*32 (u16)

typedef unsigned short u16;
typedef __attribute__((ext_vector_type(8))) short short8_t;  // 8 bf16 = 4 VGPR
typedef __attribute__((ext_vector_type(4))) float floatx4;

__device__ u16   g_xb[(size_t)BATCH * IMG_];  // x bf16 NHWC [b][pos][ch]
__device__ u16   g_h[(size_t)JOBS * IMG_];    // conv1 out bf16 NHWC [job][pos][ch]
__device__ u16   g_pw1[NE * PWSZ];            // packed conv1 w (bn1_s folded)
__device__ u16   g_pw2[NE * PWSZ];            // packed conv2 w (bn2_s folded)
__device__ int   g_eid[JOBS];
__device__ float g_wgt[JOBS];
__device__ float g_pool[BATCH * CH];          // GAP sums (atomic), zeroed by pack

__device__ __forceinline__ u16 f2b(float f) {
    unsigned v; __builtin_memcpy(&v, &f, 4);
    return (u16)((v + 0x7FFFu + ((v >> 16) & 1u)) >> 16);   // RNE
}

// ---------------- weight pre-pack + g_pool zero -----------------------------
// packed[e][s][m][kk] = w[e][m][ci][tap] * bn_s[e][m], ci=(s&1)*32+kk, tap=s>>1
__global__ __launch_bounds__(256) void pack_kernel(
    const float* __restrict__ w1, const float* __restrict__ s1,
    const float* __restrict__ w2, const float* __restrict__ s2)
{
    int idx = blockIdx.x * 256 + threadIdx.x;        // < 589824
    if (idx < BATCH*CH) g_pool[idx] = 0.f;
    int conv = idx / 294912;
    int i2 = idx - conv * 294912;
    int e = i2 / PWSZ;   int r = i2 - e * PWSZ;
    int s = r / 2048;    r -= s * 2048;
    int m = r / 32;      int kk = r - m * 32;
    int tap = s >> 1;
    int ci = ((s & 1) << 5) | kk;
    const float* w  = conv ? w2 : w1;
    const float* sc = conv ? s2 : s1;
    float v = w[((e*64 + m)*64 + ci)*9 + tap] * sc[e*64 + m];
    (conv ? g_pw2 : g_pw1)[i2] = f2b(v);
}

// ---------------- x NCHW f32 -> g_xb NHWC bf16 + GAP from LDS ---------------
__global__ __launch_bounds__(256) void xconv_kernel(const float* __restrict__ x)
{
    __shared__ u16   T [64*66];       // bf16 transpose staging
    __shared__ float Tf[64*66];       // f32 copy for exact GAP
    int b = blockIdx.y;
    int pos0 = blockIdx.x * 64;
    int tid = threadIdx.x;
    int pin = tid & 63;
    int c0 = tid >> 6;                // 0..3
    const float* xb = x + (size_t)b*IMG_ + pos0 + pin;
    #pragma unroll
    for (int i = 0; i < 16; i++) {
        int ch = c0*16 + i;
        float v = xb[ch*HW_];               // coalesced 256B f32 read per instr
        T [pin*66 + ch] = f2b(v);
        Tf[pin*66 + ch] = v;
    }
    __syncthreads();
    u16* ob = g_xb + (size_t)b*IMG_ + (size_t)pos0*64;
    #pragma unroll
    for (int i = 0; i < 16; i++) {
        int j = tid + i*256;          // 0..4095
        int ch = j & 63, pos = j >> 6;
        ob[pos*64 + ch] = T[pos*66 + ch];   // coalesced 512B write per instr
    }
    if (tid < 64) {                   // exact f32 GAP partial from LDS
        float s = 0.f;
        #pragma unroll 8
        for (int p = 0; p < 64; p++) s += Tf[p*66 + tid];
        atomicAdd(&g_pool[b*64 + tid], s);
    }
}

// ---------------- gate finalize: pool -> logits -> top2 softmax -------------
__global__ __launch_bounds__(64) void gate_fin_kernel(
    const float* __restrict__ gw, const float* __restrict__ gb,
    float* __restrict__ dw_out)
{
    __shared__ float pooled[CH];
    __shared__ float logits[NE];
    int b = blockIdx.x, t = threadIdx.x;
    pooled[t] = g_pool[b*64 + t] * (1.f/3136.f);
    __syncthreads();
    if (t < NE) {
        float l = gb[t];
        for (int c = 0; c < CH; c++) l += pooled[c] * gw[t*CH + c];
        logits[t] = l;
    }
    __syncthreads();
    if (t == 0) {
        int i1 = 0; float v1 = logits[0];
        for (int e = 1; e < NE; e++) if (logits[e] > v1) { v1 = logits[e]; i1 = e; }
        int i2 = -1; float v2 = -3.4e38f;
        for (int e = 0; e < NE; e++) if (e != i1 && logits[e] > v2) { v2 = logits[e]; i2 = e; }
        float eb = __expf(v2 - v1);
        float wa = 1.f / (1.f + eb), wb = eb / (1.f + eb);
        for (int e = 0; e < NE; e++) dw_out[b*NE + e] = 0.f;
        dw_out[b*NE + i1] = wa;
        dw_out[b*NE + i2] = wb;
        g_eid[2*b] = i1; g_eid[2*b+1] = i2;
        g_wgt[2*b] = wa; g_wgt[2*b+1] = wb;
    }
}

// B-fragment loader: one 16B NHWC load, clamped+zeroed at image edges.
// `in` is pre-offset by qk (k-quad channel offset).
__device__ __forceinline__ short8_t loadB(
    const u16* __restrict__ in, int gn, int y, int xc, int s)
{
    int tap = s >> 1;
    int dy = tap/3 - 1, dxk = tap - (tap/3)*3 - 1;
    int p = gn + dy*56 + dxk;
    bool vld = ((unsigned)(y + dy) < 56u) && ((unsigned)(xc + dxk) < 56u);
    int pc = p < 0 ? 0 : (p > 3135 ? 3135 : p);
    short8_t t = *(const short8_t*)(in + pc*64 + ((s & 1) << 5));
    const short8_t zero = {};
    return vld ? t : zero;
}

// Cooperative A chunk load: both experts, 9 K-steps, 72 KB -> AL. 512 threads.
__device__ __forceinline__ void loadA_chunk(
    u16* AL, const u16* pw0, const u16* pw1, int c, int tid)
{
    #pragma unroll 3
    for (int i = 0; i < 9; i++) {
        int u = i*512 + tid;            // 0..4607 16B-units
        int eslot = u / 2304;
        int r = u - eslot*2304;
        int sl = r >> 8;
        int off = (r & 255) * 8;
        const u16* src = (eslot ? pw1 : pw0) + (c*9 + sl)*2048 + off;
        short8_t v = *(const short8_t*)src;
        *(short8_t*)&AL[(eslot*9 + sl)*2048 + off] = v;
    }
}

// ---------------- conv1 (both experts, shared B, N=32/wave) -> g_h ----------
__global__ __launch_bounds__(512, 4) void conv1_kernel(const float* __restrict__ b1)
{
    __shared__ u16 AL[2*9*2048];        // 72 KB: [eslot][sl][m][kk]
    int tile = blockIdx.x;              // 0..12 (N=256 tiles)
    int b    = blockIdx.y;
    int e0 = g_eid[2*b], e1 = g_eid[2*b+1];
    int tid = threadIdx.x;
    int lane = tid & 63, w = tid >> 6;  // 8 waves
    int l15 = lane & 15, q = lane >> 4, qk = q*8;
    int gn0 = tile*256 + w*32 + l15;    // nf=0 position
    int gn1 = gn0 + 16;                 // nf=1 position
    int y0 = gn0/56, x0 = gn0 - y0*56;
    int y1 = gn1/56, x1 = gn1 - y1*56;
    const u16* in = g_xb + (size_t)b*IMG_ + qk;
    const u16* pw0 = g_pw1 + e0*PWSZ;
    const u16* pw1 = g_pw1 + e1*PWSZ;

    floatx4 acc[2][2][4] = {};          // [expert][nf][mb]
    short8_t B[2][2];                   // [nf][depth]
    B[0][0] = loadB(in, gn0, y0, x0, 0);
    B[1][0] = loadB(in, gn1, y1, x1, 0);
    B[0][1] = loadB(in, gn0, y0, x0, 1);
    B[1][1] = loadB(in, gn1, y1, x1, 1);

    for (int c = 0; c < 2; c++) {
        if (c) __syncthreads();
        loadA_chunk(AL, pw0, pw1, c, tid);
        __syncthreads();
        #pragma unroll
        for (int sl = 0; sl < 9; sl++) {
            int s = c*9 + sl;
            short8_t Bn0 = {}, Bn1 = {};
            if (s + 2 < 18) {
                Bn0 = loadB(in, gn0, y0, x0, s + 2);
                Bn1 = loadB(in, gn1, y1, x1, s + 2);
            }
            const u16* a0 = &AL[(0*9 + sl)*2048 + l15*32 + qk];
            const u16* a1 = &AL[(1*9 + sl)*2048 + l15*32 + qk];
            short8_t bb0 = B[0][s & 1], bb1 = B[1][s & 1];
            #pragma unroll
            for (int mb = 0; mb < 4; mb++) {
                short8_t a = *(const short8_t*)(a0 + mb*512);   // 1 ds_read
                acc[0][0][mb] = __builtin_amdgcn_mfma_f32_16x16x32_bf16(a, bb0, acc[0][0][mb], 0, 0, 0);
                acc[0][1][mb] = __builtin_amdgcn_mfma_f32_16x16x32_bf16(a, bb1, acc[0][1][mb], 0, 0, 0);
            }
            #pragma unroll
            for (int mb = 0; mb < 4; mb++) {
                short8_t a = *(const short8_t*)(a1 + mb*512);
                acc[1][0][mb] = __builtin_amdgcn_mfma_f32_16x16x32_bf16(a, bb0, acc[1][0][mb], 0, 0, 0);
                acc[1][1][mb] = __builtin_amdgcn_mfma_f32_16x16x32_bf16(a, bb1, acc[1][1][mb], 0, 0, 0);
            }
            B[0][s & 1] = Bn0; B[1][s & 1] = Bn1;
        }
    }

    #pragma unroll
    for (int nf = 0; nf < 2; nf++) {
        int gn = nf ? gn1 : gn0;
        if (gn >= HW_) continue;
        u16* hb0 = g_h + (size_t)(2*b)*IMG_ + (size_t)gn*64;
        u16* hb1 = hb0 + IMG_;
        #pragma unroll
        for (int mb = 0; mb < 4; mb++) {
            union { u16 u[4]; uint2 v; } t0, t1;
            #pragma unroll
            for (int r = 0; r < 4; r++) {
                int m = mb*16 + q*4 + r;
                t0.u[r] = f2b(fmaxf(acc[0][nf][mb][r] + b1[e0*64 + m], 0.f));
                t1.u[r] = f2b(fmaxf(acc[1][nf][mb][r] + b1[e1*64 + m], 0.f));
            }
            *(uint2*)(hb0 + mb*16 + q*4) = t0.v;
            *(uint2*)(hb1 + mb*16 + q*4) = t1.v;
        }
    }
}

// ---------------- conv2 (2 jobs x 2 nf) + bn2 + residual + combine ----------
__global__ __launch_bounds__(512, 4) void conv2_kernel(
    const float* __restrict__ x, const float* __restrict__ b2,
    float* __restrict__ out)
{
    __shared__ u16 AL[2*9*2048];        // 72 KB
    int tile = 12 - blockIdx.x;         // REVERSED: newest h first (L2 LIFO)
    int b    = 63 - blockIdx.y;
    int e0 = g_eid[2*b], e1 = g_eid[2*b+1];
    float w0 = g_wgt[2*b], w1w = g_wgt[2*b+1];
    int tid = threadIdx.x;
    int lane = tid & 63, w = tid >> 6;
    int l15 = lane & 15, q = lane >> 4, qk = q*8;
    int gn0 = tile*256 + w*32 + l15;
    int gn1 = gn0 + 16;
    int y0 = gn0/56, x0 = gn0 - y0*56;
    int y1 = gn1/56, x1 = gn1 - y1*56;
    const u16* h0 = g_h + (size_t)(2*b)*IMG_ + qk;
    const u16* h1 = h0 + IMG_;
    const u16* pw0 = g_pw2 + e0*PWSZ;
    const u16* pw1 = g_pw2 + e1*PWSZ;

    floatx4 acc[2][2][4] = {};          // [job][nf][mb]
    short8_t B0[2][2], B1[2][2];        // [nf][depth] per job
    B0[0][0] = loadB(h0, gn0, y0, x0, 0);  B1[0][0] = loadB(h1, gn0, y0, x0, 0);
    B0[1][0] = loadB(h0, gn1, y1, x1, 0);  B1[1][0] = loadB(h1, gn1, y1, x1, 0);
    B0[0][1] = loadB(h0, gn0, y0, x0, 1);  B1[0][1] = loadB(h1, gn0, y0, x0, 1);
    B0[1][1] = loadB(h0, gn1, y1, x1, 1);  B1[1][1] = loadB(h1, gn1, y1, x1, 1);

    for (int c = 0; c < 2; c++) {
        if (c) __syncthreads();
        loadA_chunk(AL, pw0, pw1, c, tid);
        __syncthreads();
        #pragma unroll
        for (int sl = 0; sl < 9; sl++) {
            int s = c*9 + sl;
            short8_t B0n0 = {}, B0n1 = {}, B1n0 = {}, B1n1 = {};
            if (s + 2 < 18) {
                B0n0 = loadB(h0, gn0, y0, x0, s + 2);
                B0n1 = loadB(h0, gn1, y1, x1, s + 2);
                B1n0 = loadB(h1, gn0, y0, x0, s + 2);
                B1n1 = loadB(h1, gn1, y1, x1, s + 2);
            }
            const u16* a0 = &AL[(0*9 + sl)*2048 + l15*32 + qk];
            const u16* a1 = &AL[(1*9 + sl)*2048 + l15*32 + qk];
            short8_t b00 = B0[0][s & 1], b01 = B0[1][s & 1];
            short8_t b10 = B1[0][s & 1], b11 = B1[1][s & 1];
            #pragma unroll
            for (int mb = 0; mb < 4; mb++) {
                short8_t a = *(const short8_t*)(a0 + mb*512);
                acc[0][0][mb] = __builtin_amdgcn_mfma_f32_16x16x32_bf16(a, b00, acc[0][0][mb], 0, 0, 0);
                acc[0][1][mb] = __builtin_amdgcn_mfma_f32_16x16x32_bf16(a, b01, acc[0][1][mb], 0, 0, 0);
            }
            #pragma unroll
            for (int mb = 0; mb < 4; mb++) {
                short8_t a = *(const short8_t*)(a1 + mb*512);
                acc[1][0][mb] = __builtin_amdgcn_mfma_f32_16x16x32_bf16(a, b10, acc[1][0][mb], 0, 0, 0);
                acc[1][1][mb] = __builtin_amdgcn_mfma_f32_16x16x32_bf16(a, b11, acc[1][1][mb], 0, 0, 0);
            }
            B0[0][s & 1] = B0n0; B0[1][s & 1] = B0n1;
            B1[0][s & 1] = B1n0; B1[1][s & 1] = B1n1;
        }
    }

    #pragma unroll
    for (int nf = 0; nf < 2; nf++) {
        int gn = nf ? gn1 : gn0;
        if (gn >= HW_) continue;
        const float* xb = x + (size_t)b*IMG_ + gn;
        float* ob = out + (size_t)b*IMG_ + gn;
        #pragma unroll
        for (int mb = 0; mb < 4; mb++)
            #pragma unroll
            for (int r = 0; r < 4; r++) {
                int m = mb*16 + q*4 + r;
                float xres = xb[m*HW_];               // exact f32 residual
                float ya = acc[0][nf][mb][r] + b2[e0*64 + m];
                float yb = acc[1][nf][mb][r] + b2[e1*64 + m];
                ob[m*HW_] = w0 * fmaxf(ya + xres, 0.f) + w1w * fmaxf(yb + xres, 0.f);
            }
    }
}

extern "C" void kernel_launch(void* const* d_in, const int* in_sizes, int n_in,
                              void* d_out, int out_size, void* d_ws, size_t ws_size,
                              hipStream_t stream) {
    const float* x   = (const float*)d_in[0];
    const float* gw  = (const float*)d_in[1];
    const float* gb  = (const float*)d_in[2];
    const float* w1  = (const float*)d_in[3];
    const float* s1  = (const float*)d_in[4];
    const float* b1  = (const float*)d_in[5];
    const float* w2  = (const float*)d_in[6];
    const float* s2  = (const float*)d_in[7];
    const float* b2  = (const float*)d_in[8];
    float* out = (float*)d_out;
    float* dw  = out + (size_t)BATCH * IMG_;   // dense_w region of d_out (f32)

    (void)d_ws; (void)ws_size;                 // zero d_ws usage (R1/R2 aborts)

    hipLaunchKernelGGL(pack_kernel, dim3(2304), dim3(256), 0, stream, w1, s1, w2, s2);
    hipLaunchKernelGGL(xconv_kernel, dim3(49, BATCH), dim3(256), 0, stream, x);
    hipLaunchKernelGGL(gate_fin_kernel, dim3(BATCH), dim3(64), 0, stream, gw, gb, dw);
    hipLaunchKernelGGL(conv1_kernel, dim3(13, BATCH), dim3(512), 0, stream, b1);
    hipLaunchKernelGGL(conv2_kernel, dim3(13, BATCH), dim3(512), 0, stream, x, b2, out);
}